// Round 5
// baseline (466.069 us; speedup 1.0000x reference)
//
#include <hip/hip_runtime.h>

// StockLSTM: A=weights / B=state MFMA layout so gate nonlinearity + cell
// update are in-register. 1024-thread blocks (16 waves, 4/SIMD), wave w owns
// hidden units j in [4w,4w+4) across all 4 gate groups; 2 barriers/step with
// t-parity double-buffered h state. bf16 hi/lo 3-term MFMA; x-term in fp32 VALU.
// __launch_bounds__(1024,4): 128-VGPR budget so weight fragments stay resident
// (R4 regression: default cap=64 VGPR spilled ~38 MB/dispatch to scratch).

#define TT   256
#define II   5
#define HH   64
#define OO   25
#define MT   16        // batch rows per block (MFMA n-dim)
#define NTHR 1024
#define XR   325       // xs row stride (floats): 320 + 5 skew
#define HR   72        // h row stride (ushorts): 64 + 8 pad (16B aligned)
#define HF   65        // h2f row stride (floats)

typedef __attribute__((ext_vector_type(8))) short  short8;
typedef __attribute__((ext_vector_type(4))) float  floatx4;

#define MFMA(a, b, c) __builtin_amdgcn_mfma_f32_16x16x32_bf16(a, b, c, 0, 0, 0)

__device__ __forceinline__ float frcp(float x) { return __builtin_amdgcn_rcpf(x); }
// clamp-free: x->+inf => exp2->inf => rcp->0 => sig->... saturates correctly
__device__ __forceinline__ float fsig(float x) {
    return frcp(1.f + __builtin_amdgcn_exp2f(x * -1.44269504f));
}
__device__ __forceinline__ float ftanhf(float x) {
    return 1.f - 2.f * frcp(1.f + __builtin_amdgcn_exp2f(x * 2.88539008f));
}
__device__ __forceinline__ unsigned short bf16_rne(float f) {
    unsigned int u = __builtin_bit_cast(unsigned int, f);
    u += 0x7FFFu + ((u >> 16) & 1u);
    return (unsigned short)(u >> 16);
}
__device__ __forceinline__ float bf16_f(unsigned short h) {
    unsigned int u = ((unsigned int)h) << 16;
    return __builtin_bit_cast(float, u);
}
struct HiLo { short hi, lo; };
__device__ __forceinline__ HiLo split2(float v) {
    HiLo r;
    unsigned short h = bf16_rne(v);
    r.hi = (short)h;
    r.lo = (short)bf16_rne(v - bf16_f(h));
    return r;
}

__global__ __launch_bounds__(NTHR, 4)
void lstm_mfma2(const float* __restrict__ x,
                const float* __restrict__ Wih0, const float* __restrict__ Whh0,
                const float* __restrict__ bih0, const float* __restrict__ bhh0,
                const float* __restrict__ Wih1, const float* __restrict__ Whh1,
                const float* __restrict__ bih1, const float* __restrict__ bhh1,
                const float* __restrict__ Wfc,  const float* __restrict__ bfc,
                float* __restrict__ out)
{
    __shared__ __align__(16) float          xs[MT * XR];          // 20.8 KB
    __shared__ __align__(16) unsigned short h1hi[2][MT * HR];     // 4.6 KB each pair
    __shared__ __align__(16) unsigned short h1lo[2][MT * HR];
    __shared__ __align__(16) unsigned short h2hi[2][MT * HR];
    __shared__ __align__(16) unsigned short h2lo[2][MT * HR];
    __shared__ __align__(16) float          h2f[MT * HF];         // 4.2 KB

    const int tid   = threadIdx.x;
    const int w     = tid >> 6;       // wave 0..15
    const int lane  = tid & 63;
    const int b     = lane & 15;      // batch col (B n-dim / C col)
    const int q     = lane >> 4;      // k-slice selector / C row-quad
    const int jmine = 4 * w + q;      // this lane's hidden unit
    const int hw_off = b * HR + jmine;

    // ---------------- A-fragment (weight) preload ----------------
    // Tile row m in [0,16): gate group = m&3, hidden j = 4w + (m>>2).
    // A layout: lane holds A[m = lane&15][k = q*8 + jj].
    short8 A1h[2], A1l[2];   // Whh0 k-chunks
    short8 A2h[4], A2l[4];   // chunks 0,1: Wih1 (h1 side); 2,3: Whh1 (h2 side)
    {
        const int rr = lane & 15;
        const int g  = (rr & 3) * 64 + 4 * w + (rr >> 2);
        #pragma unroll
        for (int c = 0; c < 2; ++c)
            #pragma unroll
            for (int jj = 0; jj < 8; ++jj) {
                HiLo s = split2(Whh0[g * HH + c * 32 + q * 8 + jj]);
                A1h[c][jj] = s.hi; A1l[c][jj] = s.lo;
            }
        #pragma unroll
        for (int c = 0; c < 4; ++c)
            #pragma unroll
            for (int jj = 0; jj < 8; ++jj) {
                const int k = c * 32 + q * 8 + jj;
                float wv = (k < HH) ? Wih1[g * HH + k] : Whh1[g * HH + (k - HH)];
                HiLo s = split2(wv);
                A2h[c][jj] = s.hi; A2l[c][jj] = s.lo;
            }
    }
    // x weights (exact fp32 VALU path) + biases, indexed by acc reg r:
    // acc[r] <-> gate row r*64 + jmine.
    float Wx[4][II], bias1[4], bias2[4];
    #pragma unroll
    for (int r = 0; r < 4; ++r) {
        const int g = r * 64 + jmine;
        bias1[r] = bih0[g] + bhh0[g];
        bias2[r] = bih1[g] + bhh1[g];
        #pragma unroll
        for (int i = 0; i < II; ++i) Wx[r][i] = Wih0[g * II + i];
    }

    // ---------------- zero h state (both parities) ----------------
    {
        unsigned int* z1 = (unsigned int*)h1hi;
        unsigned int* z2 = (unsigned int*)h1lo;
        unsigned int* z3 = (unsigned int*)h2hi;
        unsigned int* z4 = (unsigned int*)h2lo;
        for (int i = tid; i < MT * HR; i += NTHR) {  // MT*HR uints = full [2][] array
            z1[i] = 0u; z2[i] = 0u; z3[i] = 0u; z4[i] = 0u;
        }
    }
    float c1 = 0.f, c2 = 0.f;
    __syncthreads();

    for (int t = 0; t < TT; ++t) {
        // ---- refill 64-step x chunk (wave w loads batch row w) ----
        if ((t & 63) == 0) {
            const float* src = x + ((size_t)(blockIdx.x * MT + w) * TT + t) * II;
            float* dst = xs + w * XR;
            #pragma unroll
            for (int i = 0; i < 5; ++i) dst[lane + i * 64] = src[lane + i * 64];
            __syncthreads();
        }
        const int dt = t & 63;
        const int wp = t & 1, rp = wp ^ 1;
        const int off0 = b * HR + q * 8, off1 = off0 + 32;

        // ================= Layer 1 =================
        floatx4 accA, accB = {0.f, 0.f, 0.f, 0.f};
        {
            const float* xv = xs + b * XR + dt * II;
            const float x0 = xv[0], x1 = xv[1], x2 = xv[2], x3 = xv[3], x4 = xv[4];
            #pragma unroll
            for (int r = 0; r < 4; ++r)
                accA[r] = bias1[r] + Wx[r][0]*x0 + Wx[r][1]*x1 + Wx[r][2]*x2
                                   + Wx[r][3]*x3 + Wx[r][4]*x4;
        }
        {
            short8 Bh0 = *(const short8*)(&h1hi[rp][off0]);
            short8 Bl0 = *(const short8*)(&h1lo[rp][off0]);
            short8 Bh1 = *(const short8*)(&h1hi[rp][off1]);
            short8 Bl1 = *(const short8*)(&h1lo[rp][off1]);
            accA = MFMA(A1h[0], Bh0, accA);
            accA = MFMA(A1h[0], Bl0, accA);
            accA = MFMA(A1l[0], Bh0, accA);
            accB = MFMA(A1h[1], Bh1, accB);
            accB = MFMA(A1h[1], Bl1, accB);
            accB = MFMA(A1l[1], Bh1, accB);
        }
        {
            const float gi = fsig  (accA[0] + accB[0]);
            const float gf = fsig  (accA[1] + accB[1]);
            const float gz = ftanhf(accA[2] + accB[2]);
            const float go = fsig  (accA[3] + accB[3]);
            c1 = gf * c1 + gi * gz;
            const float h = go * ftanhf(c1);
            HiLo s = split2(h);
            h1hi[wp][hw_off] = (unsigned short)s.hi;
            h1lo[wp][hw_off] = (unsigned short)s.lo;
        }
        __syncthreads();

        // ================= Layer 2 =================
        #pragma unroll
        for (int r = 0; r < 4; ++r) { accA[r] = bias2[r]; accB[r] = 0.f; }
        {
            short8 Bh0 = *(const short8*)(&h1hi[wp][off0]);
            short8 Bl0 = *(const short8*)(&h1lo[wp][off0]);
            short8 Bh1 = *(const short8*)(&h1hi[wp][off1]);
            short8 Bl1 = *(const short8*)(&h1lo[wp][off1]);
            accA = MFMA(A2h[0], Bh0, accA);
            accA = MFMA(A2h[0], Bl0, accA);
            accA = MFMA(A2l[0], Bh0, accA);
            accA = MFMA(A2h[1], Bh1, accA);
            accA = MFMA(A2h[1], Bl1, accA);
            accA = MFMA(A2l[1], Bh1, accA);
        }
        {
            short8 Dh0 = *(const short8*)(&h2hi[rp][off0]);
            short8 Dl0 = *(const short8*)(&h2lo[rp][off0]);
            short8 Dh1 = *(const short8*)(&h2hi[rp][off1]);
            short8 Dl1 = *(const short8*)(&h2lo[rp][off1]);
            accB = MFMA(A2h[2], Dh0, accB);
            accB = MFMA(A2h[2], Dl0, accB);
            accB = MFMA(A2l[2], Dh0, accB);
            accB = MFMA(A2h[3], Dh1, accB);
            accB = MFMA(A2h[3], Dl1, accB);
            accB = MFMA(A2l[3], Dh1, accB);
        }
        {
            const float gi = fsig  (accA[0] + accB[0]);
            const float gf = fsig  (accA[1] + accB[1]);
            const float gz = ftanhf(accA[2] + accB[2]);
            const float go = fsig  (accA[3] + accB[3]);
            c2 = gf * c2 + gi * gz;
            const float h = go * ftanhf(c2);
            HiLo s = split2(h);
            h2hi[wp][hw_off] = (unsigned short)s.hi;
            h2lo[wp][hw_off] = (unsigned short)s.lo;
            if (t == TT - 1) h2f[b * HF + jmine] = h;
        }
        __syncthreads();
    }

    // ================= FC epilogue =================
    if (tid < MT * OO) {
        const int bb = tid / OO, o = tid - bb * OO;
        float acc = bfc[o];
        const float* wr = Wfc + o * HH;
        const float* hr = h2f + bb * HF;
        #pragma unroll
        for (int j = 0; j < HH; ++j) acc += wr[j] * hr[j];
        out[((size_t)blockIdx.x * MT + bb) * OO + o] = acc;
    }
}

extern "C" void kernel_launch(void* const* d_in, const int* in_sizes, int n_in,
                              void* d_out, int out_size, void* d_ws, size_t ws_size,
                              hipStream_t stream) {
    const float* x    = (const float*)d_in[0];
    const float* Wih0 = (const float*)d_in[1];
    const float* Whh0 = (const float*)d_in[2];
    const float* bih0 = (const float*)d_in[3];
    const float* bhh0 = (const float*)d_in[4];
    const float* Wih1 = (const float*)d_in[5];
    const float* Whh1 = (const float*)d_in[6];
    const float* bih1 = (const float*)d_in[7];
    const float* bhh1 = (const float*)d_in[8];
    const float* Wfc  = (const float*)d_in[9];
    const float* bfc  = (const float*)d_in[10];
    float* out = (float*)d_out;

    dim3 grid(4096 / MT), block(NTHR);
    lstm_mfma2<<<grid, block, 0, stream>>>(x, Wih0, Whh0, bih0, bhh0,
                                           Wih1, Whh1, bih1, bhh1,
                                           Wfc, bfc, out);
}

// Round 6
// 463.541 us; speedup vs baseline: 1.0055x; 1.0055x over previous
//
#include <hip/hip_runtime.h>

// StockLSTM: A=weights / B=state MFMA layout so gate nonlinearity + cell
// update are in-register. 1024-thread blocks (16 waves, 4/SIMD), wave w owns
// hidden units j in [4w,4w+4) across all 4 gate groups; 2 barriers/step with
// t-parity double-buffered h state. bf16 hi/lo 3-term MFMA; x-term in fp32 VALU.
// amdgpu_waves_per_eu(4,4): R4/R5 showed the default heuristic targets 8
// waves/EU -> 64 VGPRs -> ~38 MB scratch spill of loop-invariant weights.
// Forcing the occupancy range to exactly 4/EU (the block-shape limit) gives
// the allocator the full 128-VGPR budget.

#define TT   256
#define II   5
#define HH   64
#define OO   25
#define MT   16        // batch rows per block (MFMA n-dim)
#define NTHR 1024
#define XR   325       // xs row stride (floats): 320 + 5 skew
#define HR   72        // h row stride (ushorts): 64 + 8 pad (16B aligned)
#define HF   65        // h2f row stride (floats)

typedef __attribute__((ext_vector_type(8))) short  short8;
typedef __attribute__((ext_vector_type(4))) float  floatx4;

#define MFMA(a, b, c) __builtin_amdgcn_mfma_f32_16x16x32_bf16(a, b, c, 0, 0, 0)

__device__ __forceinline__ float frcp(float x) { return __builtin_amdgcn_rcpf(x); }
__device__ __forceinline__ float fsig(float x) {
    return frcp(1.f + __builtin_amdgcn_exp2f(x * -1.44269504f));
}
__device__ __forceinline__ float ftanhf(float x) {
    return 1.f - 2.f * frcp(1.f + __builtin_amdgcn_exp2f(x * 2.88539008f));
}
__device__ __forceinline__ unsigned short bf16_rne(float f) {
    unsigned int u = __builtin_bit_cast(unsigned int, f);
    u += 0x7FFFu + ((u >> 16) & 1u);
    return (unsigned short)(u >> 16);
}
__device__ __forceinline__ float bf16_f(unsigned short h) {
    unsigned int u = ((unsigned int)h) << 16;
    return __builtin_bit_cast(float, u);
}
struct HiLo { short hi, lo; };
__device__ __forceinline__ HiLo split2(float v) {
    HiLo r;
    unsigned short h = bf16_rne(v);
    r.hi = (short)h;
    r.lo = (short)bf16_rne(v - bf16_f(h));
    return r;
}

__global__ __launch_bounds__(NTHR) __attribute__((amdgpu_waves_per_eu(4, 4)))
void lstm_mfma2(const float* __restrict__ x,
                const float* __restrict__ Wih0, const float* __restrict__ Whh0,
                const float* __restrict__ bih0, const float* __restrict__ bhh0,
                const float* __restrict__ Wih1, const float* __restrict__ Whh1,
                const float* __restrict__ bih1, const float* __restrict__ bhh1,
                const float* __restrict__ Wfc,  const float* __restrict__ bfc,
                float* __restrict__ out)
{
    __shared__ __align__(16) float          xs[MT * XR];          // 20.8 KB
    __shared__ __align__(16) unsigned short h1hi[2][MT * HR];     // 4.6 KB each pair
    __shared__ __align__(16) unsigned short h1lo[2][MT * HR];
    __shared__ __align__(16) unsigned short h2hi[2][MT * HR];
    __shared__ __align__(16) unsigned short h2lo[2][MT * HR];
    __shared__ __align__(16) float          h2f[MT * HF];         // 4.2 KB

    const int tid   = threadIdx.x;
    const int w     = tid >> 6;       // wave 0..15
    const int lane  = tid & 63;
    const int b     = lane & 15;      // batch col (B n-dim / C col)
    const int q     = lane >> 4;      // k-slice selector / C row-quad
    const int jmine = 4 * w + q;      // this lane's hidden unit
    const int hw_off = b * HR + jmine;

    // ---------------- A-fragment (weight) preload ----------------
    // Tile row m in [0,16): gate group = m&3, hidden j = 4w + (m>>2).
    // A layout: lane holds A[m = lane&15][k = q*8 + jj].
    short8 A1h[2], A1l[2];   // Whh0 k-chunks
    short8 A2h[4], A2l[4];   // chunks 0,1: Wih1 (h1 side); 2,3: Whh1 (h2 side)
    {
        const int rr = lane & 15;
        const int g  = (rr & 3) * 64 + 4 * w + (rr >> 2);
        #pragma unroll
        for (int c = 0; c < 2; ++c)
            #pragma unroll
            for (int jj = 0; jj < 8; ++jj) {
                HiLo s = split2(Whh0[g * HH + c * 32 + q * 8 + jj]);
                A1h[c][jj] = s.hi; A1l[c][jj] = s.lo;
            }
        #pragma unroll
        for (int c = 0; c < 4; ++c)
            #pragma unroll
            for (int jj = 0; jj < 8; ++jj) {
                const int k = c * 32 + q * 8 + jj;
                float wv = (k < HH) ? Wih1[g * HH + k] : Whh1[g * HH + (k - HH)];
                HiLo s = split2(wv);
                A2h[c][jj] = s.hi; A2l[c][jj] = s.lo;
            }
    }
    // x weights (exact fp32 VALU path) + biases, indexed by acc reg r:
    // acc[r] <-> gate row r*64 + jmine.
    float Wx[4][II], bias1[4], bias2[4];
    #pragma unroll
    for (int r = 0; r < 4; ++r) {
        const int g = r * 64 + jmine;
        bias1[r] = bih0[g] + bhh0[g];
        bias2[r] = bih1[g] + bhh1[g];
        #pragma unroll
        for (int i = 0; i < II; ++i) Wx[r][i] = Wih0[g * II + i];
    }

    // ---------------- zero h state (both parities) ----------------
    {
        unsigned int* z1 = (unsigned int*)h1hi;
        unsigned int* z2 = (unsigned int*)h1lo;
        unsigned int* z3 = (unsigned int*)h2hi;
        unsigned int* z4 = (unsigned int*)h2lo;
        for (int i = tid; i < MT * HR; i += NTHR) {  // MT*HR uints = full [2][] array
            z1[i] = 0u; z2[i] = 0u; z3[i] = 0u; z4[i] = 0u;
        }
    }
    float c1 = 0.f, c2 = 0.f;
    __syncthreads();

    for (int t = 0; t < TT; ++t) {
        // ---- refill 64-step x chunk (wave w loads batch row w) ----
        if ((t & 63) == 0) {
            const float* src = x + ((size_t)(blockIdx.x * MT + w) * TT + t) * II;
            float* dst = xs + w * XR;
            #pragma unroll
            for (int i = 0; i < 5; ++i) dst[lane + i * 64] = src[lane + i * 64];
            __syncthreads();
        }
        const int dt = t & 63;
        const int wp = t & 1, rp = wp ^ 1;
        const int off0 = b * HR + q * 8, off1 = off0 + 32;

        // ================= Layer 1 =================
        floatx4 accA, accB = {0.f, 0.f, 0.f, 0.f};
        {
            const float* xv = xs + b * XR + dt * II;
            const float x0 = xv[0], x1 = xv[1], x2 = xv[2], x3 = xv[3], x4 = xv[4];
            #pragma unroll
            for (int r = 0; r < 4; ++r)
                accA[r] = bias1[r] + Wx[r][0]*x0 + Wx[r][1]*x1 + Wx[r][2]*x2
                                   + Wx[r][3]*x3 + Wx[r][4]*x4;
        }
        {
            short8 Bh0 = *(const short8*)(&h1hi[rp][off0]);
            short8 Bl0 = *(const short8*)(&h1lo[rp][off0]);
            short8 Bh1 = *(const short8*)(&h1hi[rp][off1]);
            short8 Bl1 = *(const short8*)(&h1lo[rp][off1]);
            accA = MFMA(A1h[0], Bh0, accA);
            accA = MFMA(A1h[0], Bl0, accA);
            accA = MFMA(A1l[0], Bh0, accA);
            accB = MFMA(A1h[1], Bh1, accB);
            accB = MFMA(A1h[1], Bl1, accB);
            accB = MFMA(A1l[1], Bh1, accB);
        }
        {
            const float gi = fsig  (accA[0] + accB[0]);
            const float gf = fsig  (accA[1] + accB[1]);
            const float gz = ftanhf(accA[2] + accB[2]);
            const float go = fsig  (accA[3] + accB[3]);
            c1 = gf * c1 + gi * gz;
            const float h = go * ftanhf(c1);
            HiLo s = split2(h);
            h1hi[wp][hw_off] = (unsigned short)s.hi;
            h1lo[wp][hw_off] = (unsigned short)s.lo;
        }
        __syncthreads();

        // ================= Layer 2 =================
        #pragma unroll
        for (int r = 0; r < 4; ++r) { accA[r] = bias2[r]; accB[r] = 0.f; }
        {
            short8 Bh0 = *(const short8*)(&h1hi[wp][off0]);
            short8 Bl0 = *(const short8*)(&h1lo[wp][off0]);
            short8 Bh1 = *(const short8*)(&h1hi[wp][off1]);
            short8 Bl1 = *(const short8*)(&h1lo[wp][off1]);
            accA = MFMA(A2h[0], Bh0, accA);
            accA = MFMA(A2h[0], Bl0, accA);
            accA = MFMA(A2l[0], Bh0, accA);
            accA = MFMA(A2h[1], Bh1, accA);
            accA = MFMA(A2h[1], Bl1, accA);
            accA = MFMA(A2l[1], Bh1, accA);
        }
        {
            short8 Dh0 = *(const short8*)(&h2hi[rp][off0]);
            short8 Dl0 = *(const short8*)(&h2lo[rp][off0]);
            short8 Dh1 = *(const short8*)(&h2hi[rp][off1]);
            short8 Dl1 = *(const short8*)(&h2lo[rp][off1]);
            accB = MFMA(A2h[2], Dh0, accB);
            accB = MFMA(A2h[2], Dl0, accB);
            accB = MFMA(A2l[2], Dh0, accB);
            accB = MFMA(A2h[3], Dh1, accB);
            accB = MFMA(A2h[3], Dl1, accB);
            accB = MFMA(A2l[3], Dh1, accB);
        }
        {
            const float gi = fsig  (accA[0] + accB[0]);
            const float gf = fsig  (accA[1] + accB[1]);
            const float gz = ftanhf(accA[2] + accB[2]);
            const float go = fsig  (accA[3] + accB[3]);
            c2 = gf * c2 + gi * gz;
            const float h = go * ftanhf(c2);
            HiLo s = split2(h);
            h2hi[wp][hw_off] = (unsigned short)s.hi;
            h2lo[wp][hw_off] = (unsigned short)s.lo;
            if (t == TT - 1) h2f[b * HF + jmine] = h;
        }
        __syncthreads();
    }

    // ================= FC epilogue =================
    if (tid < MT * OO) {
        const int bb = tid / OO, o = tid - bb * OO;
        float acc = bfc[o];
        const float* wr = Wfc + o * HH;
        const float* hr = h2f + bb * HF;
        #pragma unroll
        for (int j = 0; j < HH; ++j) acc += wr[j] * hr[j];
        out[((size_t)blockIdx.x * MT + bb) * OO + o] = acc;
    }
}

extern "C" void kernel_launch(void* const* d_in, const int* in_sizes, int n_in,
                              void* d_out, int out_size, void* d_ws, size_t ws_size,
                              hipStream_t stream) {
    const float* x    = (const float*)d_in[0];
    const float* Wih0 = (const float*)d_in[1];
    const float* Whh0 = (const float*)d_in[2];
    const float* bih0 = (const float*)d_in[3];
    const float* bhh0 = (const float*)d_in[4];
    const float* Wih1 = (const float*)d_in[5];
    const float* Whh1 = (const float*)d_in[6];
    const float* bih1 = (const float*)d_in[7];
    const float* bhh1 = (const float*)d_in[8];
    const float* Wfc  = (const float*)d_in[9];
    const float* bfc  = (const float*)d_in[10];
    float* out = (float*)d_out;

    dim3 grid(4096 / MT), block(NTHR);
    lstm_mfma2<<<grid, block, 0, stream>>>(x, Wih0, Whh0, bih0, bhh0,
                                           Wih1, Whh1, bih1, bhh1,
                                           Wfc, bfc, out);
}